// Round 10
// baseline (113.474 us; speedup 1.0000x reference)
//
#include <hip/hip_runtime.h>
#include <stdint.h>

// R7-passing structure (atomic-free mining, 111us, absmax 0.0) + producer/
// consumer XCD alignment. R9 falsified discard-prefetch (shared LDS sink
// serializes LDS-DMA: k_mine2 42->67us). Key R9 counter fact: mining dur ~=
// FETCH_SIZE / ~55GB/s every round -> mining is drained by beyond-L2 fetches
// of gH lines WRITTEN ON OTHER XCDs by the row-indexed scatter. Fix: prep
// writes slot->row map (same scan, bit-identical slots); scatter becomes
// slot-indexed with the SAME XCD swizzle as mining -> every gH/gSq line is
// produced on the XCD that mines it (dirty-local-L2 at first touch).

#define N 8192
#define D 256
#define NSUBJ 16
#define PADS 768                 // padded slot per subject (mean 512, +11 sigma safe)
#define GN (NSUBJ * PADS)        // 12288 gathered rows
#define MARGIN 1.0f

typedef __attribute__((ext_vector_type(8))) short short8;   // 8 bf16 = 4 VGPRs (MFMA A/B frag)
typedef __attribute__((ext_vector_type(4))) float f32x4;    // MFMA C/D frag
typedef __attribute__((ext_vector_type(4))) unsigned short us4;
typedef unsigned long long u64;

__device__ __forceinline__ unsigned short f2bf(float x) {
    unsigned u = __float_as_uint(x);
    u += 0x7fffu + ((u >> 16) & 1u);
    return (unsigned short)(u >> 16);
}

// ---------------- ws layout ----------------
// ushort gH[GN*D]; u64 posP[GN]; u64 negP[GN]; int gIdx[GN]; int gLab[GN];
// float gSq[GN]; int writePtr[16]; int doneS[16]; int doneG; float partialS[16];
// float partialC[16]

// Prep: same R0-proven scan (bit-identical slot assignment), but now writes
// the INVERSE map directly: gIdx[slot]=row, gLab[slot]=labels[row]. Block b
// handles subject s = 2*(b&7) + (b>>3) so subject s is written on XCD s/2
// (same XCD that mines it). Pads + doneS/doneG init as before.
__global__ void k_prep(const int* __restrict__ sbjv, const int* __restrict__ labels,
                       int* __restrict__ writePtr, int* __restrict__ gIdx,
                       int* __restrict__ gLab, int* __restrict__ doneS,
                       int* __restrict__ doneG) {
    int b = blockIdx.x;                 // 0..15
    int s = 2 * (b & 7) + (b >> 3);     // XCD-aligned subject (bijective)
    int tid = threadIdx.x;              // 256
    int lane = tid & 63, w = tid >> 6;

    #pragma unroll
    for (int it = 0; it < 3; ++it) {    // default all slots to pad
        int slot = s * PADS + it * 256 + tid;
        gIdx[slot] = -1;
        gLab[slot] = -2;
    }
    if (tid == 0) {
        doneS[s] = 0;
        if (s == 0) *doneG = 0;
    }

    __shared__ int wsum[4];
    __shared__ int carry;
    if (tid == 0) carry = s * PADS;
    __syncthreads();                    // orders pad-init before scan writes

    for (int iter = 0; iter < 8; ++iter) {          // 1024 rows per iter, int4/thread
        int r0 = iter * 1024 + tid * 4;
        int4 sv = *(const int4*)(sbjv + r0);
        int4 lv = *(const int4*)(labels + r0);
        int m0 = (sv.x == s), m1 = (sv.y == s), m2 = (sv.z == s), m3 = (sv.w == s);
        int cnt = m0 + m1 + m2 + m3;
        int x = cnt;                                 // wave inclusive scan
        #pragma unroll
        for (int o = 1; o < 64; o <<= 1) {
            int y = __shfl_up(x, o, 64);
            if (lane >= o) x += y;
        }
        if (lane == 63) wsum[w] = x;
        __syncthreads();                             // A: wsum + carry visible
        int bs = carry + (x - cnt);
        #pragma unroll
        for (int ww = 0; ww < 4; ++ww) if (ww < w) bs += wsum[ww];
        if (m0) { gIdx[bs] = r0 + 0; gLab[bs] = lv.x; ++bs; }
        if (m1) { gIdx[bs] = r0 + 1; gLab[bs] = lv.y; ++bs; }
        if (m2) { gIdx[bs] = r0 + 2; gLab[bs] = lv.z; ++bs; }
        if (m3) { gIdx[bs] = r0 + 3; gLab[bs] = lv.w; ++bs; }
        __syncthreads();                             // B: all reads of carry done
        if (tid == 0) carry += wsum[0] + wsum[1] + wsum[2] + wsum[3];
    }
    __syncthreads();
    if (tid == 0) writePtr[s] = carry;               // == s*PADS + count(s)
}

// Slot-indexed gather (replaces row-indexed scatter). 3072 blocks = 8 XCDs x
// 384; blk = (bid&7)*384 + bid>>3 -> XCD x owns slots of subjects {2x,2x+1},
// matching k_mine2's swizzle: every gH/gSq line is produced on its miner XCD.
// One wave per slot; pad slots (gIdx<0) skipped (gH/gSq garbage is masked by
// pad metadata in mining, same as R0..R9).
__global__ __launch_bounds__(256) void k_scatter2(
        const float* __restrict__ emb, const int* __restrict__ gIdx,
        unsigned short* __restrict__ gH, float* __restrict__ gSq) {
    int bid = blockIdx.x;
    int blk = (bid & 7) * 384 + (bid >> 3);      // XCD-aware remap (bijective)
    int w = threadIdx.x >> 6, lane = threadIdx.x & 63;
    int p = blk * 4 + w;
    int row = gIdx[p];
    if (row < 0) return;                         // pad slot (wave-uniform)
    float4 v = ((const float4*)(emb + (size_t)row * D))[lane];
    float s = v.x * v.x + v.y * v.y + v.z * v.z + v.w * v.w;
    #pragma unroll
    for (int o = 32; o; o >>= 1) s += __shfl_xor(s, o, 64);
    us4 h;
    h.x = f2bf(v.x); h.y = f2bf(v.y); h.z = f2bf(v.z); h.w = f2bf(v.w);
    *(us4*)(gH + (size_t)p * D + lane * 4) = h;
    if (lane == 0) gSq[p] = s;
}

// R7-passing atomic-free mining + distributed loss, VERBATIM (no burst).
// Grid: 192 blocks = 16 subjects x 12 row-tiles, XCD swizzle (2 subj/XCD).
// 512 thr (8 waves); wave w handles ctiles {w, w+8}.
__global__ __launch_bounds__(512, 1) void k_mine2(
        const unsigned short* __restrict__ gH, const int* __restrict__ gIdx,
        const int* __restrict__ gLab, const float* __restrict__ gSq,
        const int* __restrict__ writePtr,
        u64* __restrict__ posP, u64* __restrict__ negP,
        int* __restrict__ doneS, int* __restrict__ doneG,
        float* __restrict__ partialS, float* __restrict__ partialC,
        float* __restrict__ out) {
    int bid = blockIdx.x;
    int blk = (bid & 7) * 24 + (bid >> 3);      // XCD-aware remap (bijective)
    int s    = blk / 12;
    int rowt = blk % 12;
    int tid  = threadIdx.x;
    int lane = tid & 63, w = tid >> 6;          // w: 0..7
    int quad = lane >> 4, l15 = lane & 15;
    int base = s * PADS;
    int cntS = writePtr[s] - base;
    bool active = (rowt * 64 < cntS);           // block-uniform
    int i0 = base + rowt * 64;

    __shared__ u64 lbp[8][64];                  // per-wave best-pos, per row
    __shared__ u64 lbn[8][64];                  // per-wave best-neg, per row
    lbp[w][lane] = 0ull;                        // wave-local init (no race)
    lbn[w][lane] = ~0ull;

    if (active) {
        // row metadata: once per wave (shared by both ctiles)
        int labr[4][4], idxr[4][4];
        float sqr[4][4];
        #pragma unroll
        for (int mt = 0; mt < 4; ++mt)
            #pragma unroll
            for (int rg = 0; rg < 4; ++rg) {
                int r = i0 + mt * 16 + quad * 4 + rg;
                labr[mt][rg] = gLab[r]; idxr[mt][rg] = gIdx[r]; sqr[mt][rg] = gSq[r];
            }

        for (int ct = w; ct < 12; ct += 8) {    // wave-uniform trip count
            if (ct * 64 >= cntS) continue;      // wave-uniform skip (pad ctile)
            int j0 = base + ct * 64;

            int labc[4], idxc[4];
            float sqc[4];
            #pragma unroll
            for (int nt = 0; nt < 4; ++nt) {
                int cidx = j0 + nt * 16 + l15;
                labc[nt] = gLab[cidx]; idxc[nt] = gIdx[cidx]; sqc[nt] = gSq[cidx];
            }

            f32x4 acc[4][4];
            #pragma unroll
            for (int mt = 0; mt < 4; ++mt)
                #pragma unroll
                for (int nt = 0; nt < 4; ++nt) {
                    f32x4 z = {0.f, 0.f, 0.f, 0.f};
                    acc[mt][nt] = z;
                }

            #pragma unroll 2
            for (int kb = 0; kb < 8; ++kb) {
                int koff = kb * 32 + quad * 8;
                short8 a[4], b[4];
                #pragma unroll
                for (int mt = 0; mt < 4; ++mt)
                    a[mt] = *(const short8*)(gH + (size_t)(i0 + mt * 16 + l15) * D + koff);
                #pragma unroll
                for (int nt = 0; nt < 4; ++nt)
                    b[nt] = *(const short8*)(gH + (size_t)(j0 + nt * 16 + l15) * D + koff);
                #pragma unroll
                for (int mt = 0; mt < 4; ++mt)
                    #pragma unroll
                    for (int nt = 0; nt < 4; ++nt)
                        acc[mt][nt] = __builtin_amdgcn_mfma_f32_16x16x32_bf16(
                            a[mt], b[nt], acc[mt][nt], 0, 0, 0);
            }

            // ---- epilogue: C layout col = lane&15, row = quad*4 + reg ----
            #pragma unroll
            for (int mt = 0; mt < 4; ++mt) {
                u64 bp[4], bn[4];
                #pragma unroll
                for (int rg = 0; rg < 4; ++rg) { bp[rg] = 0ull; bn[rg] = ~0ull; }
                #pragma unroll
                for (int nt = 0; nt < 4; ++nt) {
                    int lc = labc[nt], ic = idxc[nt];
                    float sc = sqc[nt];
                    f32x4 v = acc[mt][nt];
                    #pragma unroll
                    for (int rg = 0; rg < 4; ++rg) {
                        float d2 = fmaxf(sqr[mt][rg] + sc - 2.0f * v[rg], 0.0f);
                        u64 db = ((u64)__float_as_uint(d2)) << 32;
                        if (lc == labr[mt][rg] && ic != idxr[mt][rg] && ic >= 0) {
                            u64 pk = db | (u64)(unsigned)(~(unsigned)ic);
                            if (pk > bp[rg]) bp[rg] = pk;
                        }
                        if (lc != labr[mt][rg] && ic >= 0) {
                            u64 nk = db | (u64)(unsigned)ic;
                            if (nk < bn[rg]) bn[rg] = nk;
                        }
                    }
                }
                #pragma unroll
                for (int o = 1; o < 16; o <<= 1) {
                    #pragma unroll
                    for (int rg = 0; rg < 4; ++rg) {
                        u64 pp = __shfl_xor(bp[rg], o, 64);
                        if (pp > bp[rg]) bp[rg] = pp;
                        u64 qq = __shfl_xor(bn[rg], o, 64);
                        if (qq < bn[rg]) bn[rg] = qq;
                    }
                }
                if (l15 == 0) {                 // lanes 0,16,32,48: quad-distinct rows
                    #pragma unroll
                    for (int rg = 0; rg < 4; ++rg) {
                        int r64 = mt * 16 + quad * 4 + rg;
                        if (bp[rg] > lbp[w][r64]) lbp[w][r64] = bp[rg];
                        if (bn[rg] < lbn[w][r64]) lbn[w][r64] = bn[rg];
                    }
                }
            }
        }
    }

    __syncthreads();                            // all waves' LDS slices ready

    // cross-wave combine + final plain store (all candidates for these 64
    // rows live in this block => value == old atomic result)
    if (tid < 64) {
        u64 P = 0ull, Nn = ~0ull;
        #pragma unroll
        for (int ww = 0; ww < 8; ++ww) {
            u64 a = lbp[ww][tid]; if (a > P)  P  = a;
            u64 b = lbn[ww][tid]; if (b < Nn) Nn = b;
        }
        if (active) {
            int r = base + rowt * 64 + tid;     // rows >= cntS: stored, never read
            __hip_atomic_store(&posP[r], P,  __ATOMIC_RELAXED, __HIP_MEMORY_SCOPE_AGENT);
            __hip_atomic_store(&negP[r], Nn, __ATOMIC_RELAXED, __HIP_MEMORY_SCOPE_AGENT);
        }
    }
    __syncthreads();

    // ---- per-subject completion cascade (12 blocks/subject) ----
    __shared__ int role;
    if (tid == 0) {
        __threadfence();                        // release wave-0's stores
        role = (atomicAdd(&doneS[s], 1) == 11); // last of 12 subject-s blocks
    }
    __syncthreads();
    if (!role) return;

    // ---- subject-s loss partial ----
    __threadfence();                            // acquire
    float S = 0.f, C = 0.f;
    #pragma unroll
    for (int k = 0; k < 2; ++k) {               // 512 thr x 2 = 1024 >= PADS
        int local = tid + 512 * k;
        if (local < cntS) {
            u64 p  = __hip_atomic_load(&posP[base + local], __ATOMIC_RELAXED,
                                       __HIP_MEMORY_SCOPE_AGENT);
            u64 nn = __hip_atomic_load(&negP[base + local], __ATOMIC_RELAXED,
                                       __HIP_MEMORY_SCOPE_AGENT);
            if (p != 0ull && nn != ~0ull) {
                float dp = sqrtf(__uint_as_float((unsigned)(p >> 32)));
                float dn = sqrtf(__uint_as_float((unsigned)(nn >> 32)));
                S += fmaxf(dp - dn + MARGIN, 0.0f);
                C += 1.0f;
            }
        }
    }
    #pragma unroll
    for (int o = 32; o; o >>= 1) {
        S += __shfl_xor(S, o, 64);
        C += __shfl_xor(C, o, 64);
    }
    __shared__ float ssS[8], ssC[8];
    if (lane == 0) { ssS[w] = S; ssC[w] = C; }
    __syncthreads();
    if (tid == 0) {
        float PS = 0.f, PC = 0.f;
        #pragma unroll
        for (int i = 0; i < 8; ++i) { PS += ssS[i]; PC += ssC[i]; }
        __hip_atomic_store(&partialS[s], PS, __ATOMIC_RELAXED, __HIP_MEMORY_SCOPE_AGENT);
        __hip_atomic_store(&partialC[s], PC, __ATOMIC_RELAXED, __HIP_MEMORY_SCOPE_AGENT);
        __threadfence();
        if (atomicAdd(doneG, 1) == 15) {        // last subject finisher
            __threadfence();
            float TS = 0.f, TC = 0.f;
            #pragma unroll
            for (int s2 = 0; s2 < NSUBJ; ++s2) {
                TS += __hip_atomic_load(&partialS[s2], __ATOMIC_RELAXED,
                                        __HIP_MEMORY_SCOPE_AGENT);
                TC += __hip_atomic_load(&partialC[s2], __ATOMIC_RELAXED,
                                        __HIP_MEMORY_SCOPE_AGENT);
            }
            out[0] = TS / (TC < 1.0f ? 1.0f : TC);
        }
    }
}

extern "C" void kernel_launch(void* const* d_in, const int* in_sizes, int n_in,
                              void* d_out, int out_size, void* d_ws, size_t ws_size,
                              hipStream_t stream) {
    const float* emb  = (const float*)d_in[0];
    const int* labels = (const int*)d_in[1];
    const int* sbjv   = (const int*)d_in[2];
    float* out = (float*)d_out;

    char* ws = (char*)d_ws;
    unsigned short* gH = (unsigned short*)ws;                 // GN*D*2 = 6291456 B
    u64* posP     = (u64*)(ws + 6291456);                     // GN*8 = 98304
    u64* negP     = (u64*)(ws + 6389760);                     // GN*8 = 98304
    int* gIdx     = (int*)(ws + 6488064);                     // GN*4 = 49152
    int* gLab     = (int*)(ws + 6537216);                     // GN*4
    float* gSq    = (float*)(ws + 6586368);                   // GN*4
    int* writePtr = (int*)(ws + 6635520);                     // 64 B
    int* doneS    = (int*)(ws + 6635584);                     // 64 B
    int* doneG    = (int*)(ws + 6635648);                     // 64 B
    float* partialS = (float*)(ws + 6635712);                 // 64 B
    float* partialC = (float*)(ws + 6635776);                 // 64 B

    k_prep<<<NSUBJ, 256, 0, stream>>>(sbjv, labels, writePtr, gIdx, gLab,
                                      doneS, doneG);
    k_scatter2<<<GN / 4, 256, 0, stream>>>(emb, gIdx, gH, gSq);
    k_mine2<<<192, 512, 0, stream>>>(gH, gIdx, gLab, gSq, writePtr,
                                     posP, negP, doneS, doneG,
                                     partialS, partialC, out);
}

// Round 11
// 100.784 us; speedup vs baseline: 1.1259x; 1.1259x over previous
//
#include <hip/hip_runtime.h>
#include <stdint.h>

// R0 (best passing config, 100.5us, absmax 0.0) VERBATIM + the single
// isolated-positive change from this session: XCD-aware tile swizzle in
// k_mine (R5->R6 A/B: -5.7us). Everything else reverted: the distributed
// loss cascade (R0->R5: +9us, device-scope fences), discard-prefetch (R9:
// +24us), XCD producer alignment (R10: null - kernel boundaries invalidate
// L2 so cross-kernel XCD placement cannot matter).

#define N 8192
#define D 256
#define NSUBJ 16
#define PADS 768                 // padded slot per subject (mean 512, +11 sigma safe)
#define GN (NSUBJ * PADS)        // 12288 gathered rows
#define MARGIN 1.0f

typedef __attribute__((ext_vector_type(8))) short short8;   // 8 bf16 = 4 VGPRs (MFMA A/B frag)
typedef __attribute__((ext_vector_type(4))) float f32x4;    // MFMA C/D frag
typedef __attribute__((ext_vector_type(4))) unsigned short us4;
typedef unsigned long long u64;

__device__ __forceinline__ unsigned short f2bf(float x) {
    unsigned u = __float_as_uint(x);
    u += 0x7fffu + ((u >> 16) & 1u);
    return (unsigned short)(u >> 16);
}

// ---------------- ws layout ----------------
// ushort gH[GN*D]; u64 posP[GN]; u64 negP[GN]; int gIdx[GN]; int gLab[GN];
// float gSq[GN]; int writePtr[16] (+pad 64B); int pos[N];

// fused: init (posP/negP/gIdx/gLab pads) + within-subject rank scan (1 block/subject)
__global__ void k_prep(const int* __restrict__ sbjv, int* __restrict__ pos,
                       int* __restrict__ writePtr, int* __restrict__ gIdx,
                       int* __restrict__ gLab, u64* __restrict__ posP,
                       u64* __restrict__ negP) {
    int s = blockIdx.x;                 // 0..15
    int tid = threadIdx.x;              // 256
    int lane = tid & 63, w = tid >> 6;

    #pragma unroll
    for (int it = 0; it < 3; ++it) {
        int slot = s * PADS + it * 256 + tid;
        gIdx[slot] = -1;
        gLab[slot] = -2;
        posP[slot] = 0ull;
        negP[slot] = ~0ull;
    }

    __shared__ int wsum[4];
    __shared__ int carry;
    if (tid == 0) carry = s * PADS;
    __syncthreads();

    for (int iter = 0; iter < 8; ++iter) {          // 1024 rows per iter, int4/thread
        int r0 = iter * 1024 + tid * 4;
        int4 sv = *(const int4*)(sbjv + r0);
        int m0 = (sv.x == s), m1 = (sv.y == s), m2 = (sv.z == s), m3 = (sv.w == s);
        int cnt = m0 + m1 + m2 + m3;
        int x = cnt;                                 // wave inclusive scan
        #pragma unroll
        for (int o = 1; o < 64; o <<= 1) {
            int y = __shfl_up(x, o, 64);
            if (lane >= o) x += y;
        }
        if (lane == 63) wsum[w] = x;
        __syncthreads();                             // A: wsum + carry visible
        int b = carry + (x - cnt);
        #pragma unroll
        for (int ww = 0; ww < 4; ++ww) if (ww < w) b += wsum[ww];
        if (m0) pos[r0 + 0] = b++;
        if (m1) pos[r0 + 1] = b++;
        if (m2) pos[r0 + 2] = b++;
        if (m3) pos[r0 + 3] = b++;
        __syncthreads();                             // B: all reads of carry done
        if (tid == 0) carry += wsum[0] + wsum[1] + wsum[2] + wsum[3];
    }
    __syncthreads();
    if (tid == 0) writePtr[s] = carry;               // == s*PADS + count(s)
}

// gather rows by subject into precomputed slots; fp32 -> bf16; fold in sq-norm
__global__ void k_scatter(const float* __restrict__ emb, const int* __restrict__ labels,
                          const int* __restrict__ sbjv, const int* __restrict__ pos,
                          unsigned short* __restrict__ gH, int* __restrict__ gIdx,
                          int* __restrict__ gLab, float* __restrict__ gSq) {
    int wave = threadIdx.x >> 6;
    int lane = threadIdx.x & 63;
    int row = blockIdx.x * 4 + wave;
    const float4* e4 = (const float4*)(emb + (size_t)row * D);
    float4 v = e4[lane];
    float s = v.x * v.x + v.y * v.y + v.z * v.z + v.w * v.w;
    #pragma unroll
    for (int o = 32; o; o >>= 1) s += __shfl_xor(s, o, 64);
    int p = pos[row];                    // wave-uniform load, no atomics
    us4 h;
    h.x = f2bf(v.x); h.y = f2bf(v.y); h.z = f2bf(v.z); h.w = f2bf(v.w);
    *(us4*)(gH + (size_t)p * D + lane * 4) = h;
    if (lane == 0) { gIdx[p] = row; gLab[p] = labels[row]; gSq[p] = s; }
}

// barrier-free mining: each WAVE owns one 64x64 tile, MFMA frags loaded
// directly from global (gH is L1/L2-hot). No LDS, no __syncthreads.
// grid: 576 blocks, XCD swizzle (R6's isolated -5.7us win): 576 = 8 XCDs x
// 72 tiles; blk = (bid%8)*72 + bid/8 (bijective) -> XCD x mines subjects
// {2x, 2x+1}: per-XCD gH read set ~0.6MB fits 4MB L2.
__global__ __launch_bounds__(256) void k_mine(
        const unsigned short* __restrict__ gH, const int* __restrict__ gIdx,
        const int* __restrict__ gLab, const float* __restrict__ gSq,
        const int* __restrict__ writePtr,
        u64* __restrict__ posP, u64* __restrict__ negP) {
    int bid = blockIdx.x;
    int blk = (bid & 7) * 72 + (bid >> 3);      // XCD-aware tile remap
    int s   = blk / 36;
    int rem = blk % 36;
    int rowt = rem / 3, cg = rem % 3;

    int tid  = threadIdx.x;
    int lane = tid & 63, w = tid >> 6;
    int quad = lane >> 4, l15 = lane & 15;
    int ctile = cg * 4 + w;

    int base = s * PADS;
    int cntS = writePtr[s] - base;
    if (rowt * 64 >= cntS || ctile * 64 >= cntS) return;   // wave-uniform exit
    int i0 = base + rowt * 64;
    int j0 = base + ctile * 64;

    // column metadata (coalesced over l15)
    int labc[4], idxc[4];
    float sqc[4];
    #pragma unroll
    for (int nt = 0; nt < 4; ++nt) {
        int c = j0 + nt * 16 + l15;
        labc[nt] = gLab[c]; idxc[nt] = gIdx[c]; sqc[nt] = gSq[c];
    }
    // row metadata (16-lane broadcast loads, L1-served)
    int labr[4][4], idxr[4][4];
    float sqr[4][4];
    #pragma unroll
    for (int mt = 0; mt < 4; ++mt)
        #pragma unroll
        for (int rg = 0; rg < 4; ++rg) {
            int r = i0 + mt * 16 + quad * 4 + rg;
            labr[mt][rg] = gLab[r]; idxr[mt][rg] = gIdx[r]; sqr[mt][rg] = gSq[r];
        }

    f32x4 acc[4][4];
    #pragma unroll
    for (int mt = 0; mt < 4; ++mt)
        #pragma unroll
        for (int nt = 0; nt < 4; ++nt) {
            f32x4 z = {0.f, 0.f, 0.f, 0.f};
            acc[mt][nt] = z;
        }

    #pragma unroll 2
    for (int kb = 0; kb < 8; ++kb) {
        int koff = kb * 32 + quad * 8;
        short8 a[4], b[4];
        #pragma unroll
        for (int mt = 0; mt < 4; ++mt)
            a[mt] = *(const short8*)(gH + (size_t)(i0 + mt * 16 + l15) * D + koff);
        #pragma unroll
        for (int nt = 0; nt < 4; ++nt)
            b[nt] = *(const short8*)(gH + (size_t)(j0 + nt * 16 + l15) * D + koff);
        #pragma unroll
        for (int mt = 0; mt < 4; ++mt)
            #pragma unroll
            for (int nt = 0; nt < 4; ++nt)
                acc[mt][nt] = __builtin_amdgcn_mfma_f32_16x16x32_bf16(
                    a[mt], b[nt], acc[mt][nt], 0, 0, 0);
    }

    // ---- mining epilogue: C layout col = lane&15, row = quad*4 + reg ----
    #pragma unroll
    for (int mt = 0; mt < 4; ++mt) {
        u64 bp[4], bn[4];
        #pragma unroll
        for (int rg = 0; rg < 4; ++rg) { bp[rg] = 0ull; bn[rg] = ~0ull; }
        #pragma unroll
        for (int nt = 0; nt < 4; ++nt) {
            int lc = labc[nt], ic = idxc[nt];
            float sc = sqc[nt];
            f32x4 v = acc[mt][nt];
            #pragma unroll
            for (int rg = 0; rg < 4; ++rg) {
                float d2 = fmaxf(sqr[mt][rg] + sc - 2.0f * v[rg], 0.0f);
                u64 db = ((u64)__float_as_uint(d2)) << 32;
                if (lc == labr[mt][rg] && ic != idxr[mt][rg] && ic >= 0) {
                    u64 pk = db | (u64)(unsigned)(~(unsigned)ic);
                    if (pk > bp[rg]) bp[rg] = pk;
                }
                if (lc != labr[mt][rg] && ic >= 0) {
                    u64 nk = db | (u64)(unsigned)ic;
                    if (nk < bn[rg]) bn[rg] = nk;
                }
            }
        }
        #pragma unroll
        for (int o = 1; o < 16; o <<= 1) {
            #pragma unroll
            for (int rg = 0; rg < 4; ++rg) {
                u64 pp = __shfl_xor(bp[rg], o, 64);
                if (pp > bp[rg]) bp[rg] = pp;
                u64 qq = __shfl_xor(bn[rg], o, 64);
                if (qq < bn[rg]) bn[rg] = qq;
            }
        }
        if (l15 == 0) {
            #pragma unroll
            for (int rg = 0; rg < 4; ++rg) {
                int r = i0 + mt * 16 + quad * 4 + rg;
                if (bp[rg]) atomicMax(&posP[r], bp[rg]);
                if (bn[rg] != ~0ull) atomicMin(&negP[r], bn[rg]);
            }
        }
    }
}

// single-block: hinge from mined d^2 (bf16-accurate, well within threshold) + mean
__global__ void k_loss(const u64* __restrict__ posP, const u64* __restrict__ negP,
                       float* __restrict__ out) {
    int tid = threadIdx.x;               // 1024
    float sum = 0.0f, cnt = 0.0f;
    for (int r = tid; r < GN; r += 1024) {
        u64 p  = posP[r];
        u64 nn = negP[r];
        if (p != 0ull && nn != ~0ull) {
            float dp = sqrtf(__uint_as_float((unsigned)(p >> 32)));
            float dn = sqrtf(__uint_as_float((unsigned)(nn >> 32)));
            sum += fmaxf(dp - dn + MARGIN, 0.0f);
            cnt += 1.0f;
        }
    }
    #pragma unroll
    for (int o = 32; o; o >>= 1) {
        sum += __shfl_xor(sum, o, 64);
        cnt += __shfl_xor(cnt, o, 64);
    }
    __shared__ float ss[16], sc[16];
    int w = tid >> 6, lane = tid & 63;
    if (lane == 0) { ss[w] = sum; sc[w] = cnt; }
    __syncthreads();
    if (tid == 0) {
        float S = 0.0f, C = 0.0f;
        #pragma unroll
        for (int i = 0; i < 16; ++i) { S += ss[i]; C += sc[i]; }
        out[0] = S / (C < 1.0f ? 1.0f : C);
    }
}

extern "C" void kernel_launch(void* const* d_in, const int* in_sizes, int n_in,
                              void* d_out, int out_size, void* d_ws, size_t ws_size,
                              hipStream_t stream) {
    const float* emb  = (const float*)d_in[0];
    const int* labels = (const int*)d_in[1];
    const int* sbjv   = (const int*)d_in[2];
    float* out = (float*)d_out;

    char* ws = (char*)d_ws;
    unsigned short* gH = (unsigned short*)ws;                 // GN*D*2 = 6291456 B
    u64* posP = (u64*)(ws + 6291456);                         // GN*8 = 98304
    u64* negP = (u64*)(ws + 6389760);                         // GN*8 = 98304
    int* gIdx = (int*)(ws + 6488064);                         // GN*4 = 49152
    int* gLab = (int*)(ws + 6537216);
    float* gSq = (float*)(ws + 6586368);
    int* writePtr = (int*)(ws + 6635520);                     // 64 B
    int* pos = (int*)(ws + 6635584);                          // N*4 = 32768

    k_prep<<<NSUBJ, 256, 0, stream>>>(sbjv, pos, writePtr, gIdx, gLab, posP, negP);
    k_scatter<<<N / 4, 256, 0, stream>>>(emb, labels, sbjv, pos, gH, gIdx, gLab, gSq);
    k_mine<<<NSUBJ * 12 * 3, 256, 0, stream>>>(gH, gIdx, gLab, gSq, writePtr, posP, negP);
    k_loss<<<1, 1024, 0, stream>>>(posP, negP, out);
}